// Round 9
// baseline (154.699 us; speedup 1.0000x reference)
//
#include <hip/hip_runtime.h>

#define B_     128
#define S_     256
#define MW_    21
#define VOCAB_ 100
#define EC_    50
#define EW_    256
#define KW_    5
#define T_     17              // MW - K + 1
#define NW_    (B_ * S_)       // 32768 words
#define GROWS  (VOCAB_ * KW_)  // 500
#define WPB    32              // words per mega block (small => 2 blocks/CU)

typedef _Float16 f16x8 __attribute__((ext_vector_type(8)));
typedef float    f32x4 __attribute__((ext_vector_type(4)));

// ---------------- kernel 1: prep
// blocks [0,500): g[v*5+k][o] = sum_i emb[v][i]*conv_w[o][i][k]  (fp16, row-major [500][256])
// blocks [500,532): Wp/Wg f32 -> fp16 in MFMA B-fragment order:
//   frag f = nt*8+ks, lane l holds W[nt*16+(l&15)][ks*32+(l>>4)*8 + j]
__global__ __launch_bounds__(256) void k_prep(const float* __restrict__ emb,
                                              const float* __restrict__ cw,
                                              const float* __restrict__ Wp,
                                              const float* __restrict__ Wg,
                                              _Float16* __restrict__ g,
                                              _Float16* __restrict__ wpf,
                                              _Float16* __restrict__ wgf) {
  const int bi = blockIdx.x;
  if (bi < GROWS) {
    __shared__ float es[EC_];
    const int v = bi / KW_;
    const int k = bi % KW_;
    const int o = threadIdx.x;
    if (threadIdx.x < EC_) es[threadIdx.x] = emb[v * EC_ + threadIdx.x];
    __syncthreads();
    float acc = 0.f;
#pragma unroll
    for (int i = 0; i < EC_; ++i)
      acc += es[i] * cw[(o * EC_ + i) * KW_ + k];
    g[bi * EW_ + o] = (_Float16)acc;
  } else {
    const int fl  = (bi - GROWS) * 256 + threadIdx.x;  // 0..8191 lane-frags
    const int nt  = fl >> 9;
    const int rem = fl & 511;
    const int ks  = rem >> 6;
    const int l   = rem & 63;
    const int n   = nt * 16 + (l & 15);
    const int kc  = ks * 32 + (l >> 4) * 8;
    const int src = n * EW_ + kc;
    const float4 p0 = *(const float4*)&Wp[src], p1 = *(const float4*)&Wp[src + 4];
    const float4 q0 = *(const float4*)&Wg[src], q1 = *(const float4*)&Wg[src + 4];
    f16x8 hp = {(_Float16)p0.x, (_Float16)p0.y, (_Float16)p0.z, (_Float16)p0.w,
                (_Float16)p1.x, (_Float16)p1.y, (_Float16)p1.z, (_Float16)p1.w};
    f16x8 hg = {(_Float16)q0.x, (_Float16)q0.y, (_Float16)q0.z, (_Float16)q0.w,
                (_Float16)q1.x, (_Float16)q1.y, (_Float16)q1.z, (_Float16)q1.w};
    *(f16x8*)&wpf[fl * 8] = hp;
    *(f16x8*)&wgf[fl * 8] = hg;
  }
}

// ---------------- kernel 2: mega — conv+relu+maxpool (A) + dual-GEMM highway (B)
// 256 threads (4 waves), 32 words/block, LDS = 16384 (y_s) + 64000 (g_s) = 80384 B
// => exactly 2 blocks/CU resident; two blocks overlap staging/barriers vs gather.
__global__ __launch_bounds__(256, 2) void k_mega(const int* __restrict__ idx,
                                                 const _Float16* __restrict__ g,
                                                 const float* __restrict__ cb,
                                                 const _Float16* __restrict__ wpf,
                                                 const _Float16* __restrict__ wgf,
                                                 const float* __restrict__ bp,
                                                 const float* __restrict__ bg,
                                                 float* __restrict__ out) {
  __shared__ __align__(16) _Float16 lds[8192 + GROWS * 64];
  _Float16* y_s = lds;            // 8192 halves: frag(mt,ks)*512 + lane*8 + j  (mt 0..1)
  _Float16* g_s = lds + 8192;     // [500][64] plain stride-64 (empirically minimal conflicts)

  const int tid  = threadIdx.x;
  const int wave = tid >> 6, lane = tid & 63;
  const int m0 = blockIdx.x * WPB;

  // ======== phase A: conv + relu + maxpool -> y_s fragments ========
  const int wq = lane >> 3, og = lane & 7;   // 8 words x 8 channel-octets per wave
#pragma unroll
  for (int chunk = 0; chunk < 4; ++chunk) {
    const int oc0 = chunk * 64;
    for (int c = tid; c < GROWS * 8; c += 256) {
      const int row = c >> 3, cc = c & 7;
      *(f16x8*)&g_s[row * 64 + cc * 8] = *(const f16x8*)&g[row * EW_ + oc0 + cc * 8];
    }
    __syncthreads();

    f16x8 bias;
#pragma unroll
    for (int j = 0; j < 8; ++j) bias[j] = (_Float16)cb[oc0 + og * 8 + j];

    const int ks_w    = chunk * 2 + (og >> 2);       // frag k-slice this octet lands in
    const int lane_hi = (og & 3) << 4;               // quad part of target lane

    const int wl = wave * 8 + wq;                    // word 0..31
    const int* __restrict__ ip = idx + (m0 + wl) * MW_;
    int base[MW_];
#pragma unroll
    for (int c = 0; c < MW_; ++c)
      base[c] = ip[c] * (KW_ * 64) + og * 8;

    const _Float16 NEG = (_Float16)(-60000.0f);
    f16x8 mx = {NEG, NEG, NEG, NEG, NEG, NEG, NEG, NEG};
#pragma unroll
    for (int t = 0; t < T_; ++t) {
      f16x8 s = *(const f16x8*)&g_s[base[t]];              // k = 0
#pragma unroll
      for (int k = 1; k < KW_; ++k)
        s += *(const f16x8*)&g_s[base[t + k] + k * 64];    // v_pk_add_f16
      mx = __builtin_elementwise_max(mx, s);               // v_pk_max_f16
    }
    // relu(bias + max_t s) == max_t relu(bias + s)
    const f16x8 zero8 = {0, 0, 0, 0, 0, 0, 0, 0};
    mx = __builtin_elementwise_max(mx + bias, zero8);

    const int mt = wl >> 4;
    const int lane_t = (wl & 15) | lane_hi;
    *(f16x8*)&y_s[((mt * 8 + ks_w) * 64 + lane_t) * 8] = mx;
    __syncthreads();  // y_s chunk complete; g_s safe to restage
  }

  // ======== phase B: dual GEMM + highway — B streamed from L1/L2, no barriers ========
  const int mt = wave >> 1, nh = wave & 1;   // 2 m-tiles x 2 n-halves
  const int quad = lane >> 4, r16 = lane & 15;

  f16x8 a[8];
#pragma unroll
  for (int ks = 0; ks < 8; ++ks)
    a[ks] = *(const f16x8*)&y_s[((mt * 8 + ks) * 64 + lane) * 8];

  const f32x4 zero = {0.f, 0.f, 0.f, 0.f};
  f32x4 accp[8], accg[8];
#pragma unroll
  for (int nf = 0; nf < 8; ++nf) { accp[nf] = zero; accg[nf] = zero; }

#pragma unroll
  for (int nf = 0; nf < 8; ++nf) {
    const int nt = nh * 8 + nf;
#pragma unroll
    for (int ks = 0; ks < 8; ++ks) {
      const int off = ((nt * 8 + ks) * 64 + lane) * 8;
      const f16x8 bpv = *(const f16x8*)&wpf[off];
      const f16x8 bgv = *(const f16x8*)&wgf[off];
      accp[nf] = __builtin_amdgcn_mfma_f32_16x16x32_f16(a[ks], bpv, accp[nf], 0, 0, 0);
      accg[nf] = __builtin_amdgcn_mfma_f32_16x16x32_f16(a[ks], bgv, accg[nf], 0, 0, 0);
    }
  }

  // epilogue
#pragma unroll
  for (int nf = 0; nf < 8; ++nf) {
    const int n = nh * 128 + nf * 16 + r16;
    const float bpn = bp[n];
    const float bgn = bg[n];
    const int ks_e = n >> 5;
    const int lane_e = ((n >> 3) & 3) << 4;
    const int je = n & 7;
#pragma unroll
    for (int reg = 0; reg < 4; ++reg) {
      const int m = mt * 16 + quad * 4 + reg;
      float p = fmaxf(accp[nf][reg] + bpn, 0.f);
      const float gz = accg[nf][reg] + bgn;
      const float gate = 1.f / (1.f + __expf(-gz));
      const float yv = (float)y_s[((mt * 8 + ks_e) * 64 + ((m & 15) | lane_e)) * 8 + je];
      out[(m0 + m) * EW_ + n] = gate * p + (1.f - gate) * yv;
    }
  }
}

extern "C" void kernel_launch(void* const* d_in, const int* in_sizes, int n_in,
                              void* d_out, int out_size, void* d_ws, size_t ws_size,
                              hipStream_t stream) {
  (void)in_sizes; (void)n_in; (void)out_size; (void)ws_size;
  const int*   idx = (const int*)d_in[0];
  const float* emb = (const float*)d_in[1];
  const float* cw  = (const float*)d_in[2];
  const float* cb  = (const float*)d_in[3];
  const float* wp  = (const float*)d_in[4];
  const float* bpp = (const float*)d_in[5];
  const float* wgt = (const float*)d_in[6];
  const float* bgg = (const float*)d_in[7];
  float* out = (float*)d_out;
  _Float16* g_ws = (_Float16*)d_ws;            // 500*256 fp16
  _Float16* wp_f = g_ws + GROWS * EW_;         // 65536 halves, frag order
  _Float16* wg_f = wp_f + EW_ * EW_;           // 65536 halves, frag order

  k_prep<<<GROWS + 32, 256, 0, stream>>>(emb, cw, wp, wgt, g_ws, wp_f, wg_f);
  k_mega<<<NW_ / WPB, 256, 0, stream>>>(idx, g_ws, cb, wp_f, wg_f, bpp, bgg, out);
}

// Round 10
// 125.289 us; speedup vs baseline: 1.2347x; 1.2347x over previous
//
#include <hip/hip_runtime.h>

#define B_     128
#define S_     256
#define MW_    21
#define VOCAB_ 100
#define EC_    50
#define EW_    256
#define KW_    5
#define T_     17              // MW - K + 1
#define NW_    (B_ * S_)       // 32768 words
#define GROWS  (VOCAB_ * KW_)  // 500
#define WPB    128             // words per mega block

typedef _Float16 f16x8 __attribute__((ext_vector_type(8)));
typedef float    f32x4 __attribute__((ext_vector_type(4)));

// ---------------- kernel 1: prep
// blocks [0,500): g[v*5+k][o] = sum_i emb[v][i]*conv_w[o][i][k]  (fp16, row-major [500][256])
// blocks [500,532): Wp/Wg f32 -> fp16 in MFMA B-fragment order:
//   frag f = nt*8+ks, lane l holds W[nt*16+(l&15)][ks*32+(l>>4)*8 + j]
__global__ __launch_bounds__(256) void k_prep(const float* __restrict__ emb,
                                              const float* __restrict__ cw,
                                              const float* __restrict__ Wp,
                                              const float* __restrict__ Wg,
                                              _Float16* __restrict__ g,
                                              _Float16* __restrict__ wpf,
                                              _Float16* __restrict__ wgf) {
  const int bi = blockIdx.x;
  if (bi < GROWS) {
    __shared__ float es[EC_];
    const int v = bi / KW_;
    const int k = bi % KW_;
    const int o = threadIdx.x;
    if (threadIdx.x < EC_) es[threadIdx.x] = emb[v * EC_ + threadIdx.x];
    __syncthreads();
    float acc = 0.f;
#pragma unroll
    for (int i = 0; i < EC_; ++i)
      acc += es[i] * cw[(o * EC_ + i) * KW_ + k];
    g[bi * EW_ + o] = (_Float16)acc;
  } else {
    const int fl  = (bi - GROWS) * 256 + threadIdx.x;  // 0..8191 lane-frags
    const int nt  = fl >> 9;
    const int rem = fl & 511;
    const int ks  = rem >> 6;
    const int l   = rem & 63;
    const int n   = nt * 16 + (l & 15);
    const int kc  = ks * 32 + (l >> 4) * 8;
    const int src = n * EW_ + kc;
    const float4 p0 = *(const float4*)&Wp[src], p1 = *(const float4*)&Wp[src + 4];
    const float4 q0 = *(const float4*)&Wg[src], q1 = *(const float4*)&Wg[src + 4];
    f16x8 hp = {(_Float16)p0.x, (_Float16)p0.y, (_Float16)p0.z, (_Float16)p0.w,
                (_Float16)p1.x, (_Float16)p1.y, (_Float16)p1.z, (_Float16)p1.w};
    f16x8 hg = {(_Float16)q0.x, (_Float16)q0.y, (_Float16)q0.z, (_Float16)q0.w,
                (_Float16)q1.x, (_Float16)q1.y, (_Float16)q1.z, (_Float16)q1.w};
    *(f16x8*)&wpf[fl * 8] = hp;
    *(f16x8*)&wgf[fl * 8] = hg;
  }
}

// ---------------- kernel 2: mega — conv+relu+maxpool (A) + dual-GEMM highway (B)
// WPB=128, 512 thr, LDS = y_s 65536 + g_s 64000 = 129536 B, 1 block/CU, 8 waves.
// g_s: plain stride-64 (empirically minimal conflicts: R4/R6 vs GST72/XOR).
// y_s: A-fragment layout with granule-low6 = lane_t ^ og  (kills 8-way write conflict;
//      reads use key = ((ks&1)<<2)|quad == writer og, still a within-frag permutation).
// g staging: chunk c+1 prefetched into registers during gather of chunk c, dumped
//      to LDS after the barrier -> no global vmcnt drain at the barrier.
__global__ __launch_bounds__(512, 2) void k_mega(const int* __restrict__ idx,
                                                 const _Float16* __restrict__ g,
                                                 const float* __restrict__ cb,
                                                 const _Float16* __restrict__ wpf,
                                                 const _Float16* __restrict__ wgf,
                                                 const float* __restrict__ bp,
                                                 const float* __restrict__ bg,
                                                 float* __restrict__ out) {
  __shared__ __align__(16) _Float16 lds[32768 + GROWS * 64];
  _Float16* y_s = lds;            // 32768 halves: (frag*64 + (lane_t^og)) * 8 + j
  _Float16* g_s = lds + 32768;    // [500][64]

  const int tid  = threadIdx.x;
  const int wave = tid >> 6, lane = tid & 63;
  const int m0 = blockIdx.x * WPB;
  const int wq = lane >> 3, og = lane & 7;   // 8 words x 8 channel-octets per wave

  // initial stage: chunk 0
#pragma unroll
  for (int i = 0; i < 8; ++i) {
    const int c = tid + i * 512;
    if (c < GROWS * 8) {
      const int row = c >> 3, cc = c & 7;
      *(f16x8*)&g_s[row * 64 + cc * 8] = *(const f16x8*)&g[row * EW_ + cc * 8];
    }
  }
  __syncthreads();

  f16x8 pre[8];
#pragma unroll
  for (int chunk = 0; chunk < 4; ++chunk) {
    const int oc0 = chunk * 64;
    // issue next chunk's loads into registers (waited only at the ds_write below)
    if (chunk < 3) {
#pragma unroll
      for (int i = 0; i < 8; ++i) {
        const int c = tid + i * 512;
        if (c < GROWS * 8) {
          const int row = c >> 3, cc = c & 7;
          pre[i] = *(const f16x8*)&g[row * EW_ + oc0 + 64 + cc * 8];
        }
      }
    }

    f16x8 bias;
#pragma unroll
    for (int j = 0; j < 8; ++j) bias[j] = (_Float16)cb[oc0 + og * 8 + j];

    const int ks_w    = chunk * 2 + (og >> 2);
    const int lane_hi = (og & 3) << 4;

#pragma unroll
    for (int it = 0; it < 2; ++it) {
      const int wl = it * 64 + wave * 8 + wq;
      const int* __restrict__ ip = idx + (m0 + wl) * MW_;
      int base[MW_];
#pragma unroll
      for (int c = 0; c < MW_; ++c)
        base[c] = ip[c] * (KW_ * 64) + og * 8;

      const _Float16 NEG = (_Float16)(-60000.0f);
      f16x8 mx = {NEG, NEG, NEG, NEG, NEG, NEG, NEG, NEG};
#pragma unroll
      for (int t = 0; t < T_; ++t) {
        f16x8 s = *(const f16x8*)&g_s[base[t]];              // k = 0
#pragma unroll
        for (int k = 1; k < KW_; ++k)
          s += *(const f16x8*)&g_s[base[t + k] + k * 64];    // v_pk_add_f16
        mx = __builtin_elementwise_max(mx, s);               // v_pk_max_f16
      }
      // relu(bias + max_t s) == max_t relu(bias + s)
      const f16x8 zero8 = {0, 0, 0, 0, 0, 0, 0, 0};
      mx = __builtin_elementwise_max(mx + bias, zero8);

      const int mt = wl >> 4;
      const int lt = ((wl & 15) | lane_hi) ^ og;             // swizzled granule low-6
      *(f16x8*)&y_s[((mt * 8 + ks_w) * 64 + lt) * 8] = mx;
    }
    __syncthreads();  // gather(c)+y-writes complete; g_s free
    if (chunk < 3) {
#pragma unroll
      for (int i = 0; i < 8; ++i) {
        const int c = tid + i * 512;
        if (c < GROWS * 8) {
          const int row = c >> 3, cc = c & 7;
          *(f16x8*)&g_s[row * 64 + cc * 8] = pre[i];
        }
      }
      __syncthreads();
    }
  }

  // ======== phase B: dual GEMM + highway — B streamed from L2, no barriers ========
  const int mtp = wave >> 1, nh = wave & 1;
  const int quad = lane >> 4, r16 = lane & 15;

  f16x8 a[2][8];
#pragma unroll
  for (int mi = 0; mi < 2; ++mi)
#pragma unroll
    for (int ks = 0; ks < 8; ++ks) {
      const int key = ((ks & 1) << 2) | quad;                // == writer og
      a[mi][ks] = *(const f16x8*)&y_s[(((mtp * 2 + mi) * 8 + ks) * 64 + (lane ^ key)) * 8];
    }

  const f32x4 zero = {0.f, 0.f, 0.f, 0.f};
#pragma unroll
  for (int h = 0; h < 2; ++h) {   // n-half: cols h*128 .. h*128+127
    f32x4 accp[2][4], accg[2][4];
#pragma unroll
    for (int mi = 0; mi < 2; ++mi)
#pragma unroll
      for (int nf = 0; nf < 4; ++nf) { accp[mi][nf] = zero; accg[mi][nf] = zero; }

#pragma unroll
    for (int nf = 0; nf < 4; ++nf) {
      const int nt = h * 8 + nh * 4 + nf;
#pragma unroll
      for (int ks = 0; ks < 8; ++ks) {
        const int off = ((nt * 8 + ks) * 64 + lane) * 8;
        const f16x8 bpv = *(const f16x8*)&wpf[off];
        const f16x8 bgv = *(const f16x8*)&wgf[off];
#pragma unroll
        for (int mi = 0; mi < 2; ++mi) {
          accp[mi][nf] = __builtin_amdgcn_mfma_f32_16x16x32_f16(a[mi][ks], bpv, accp[mi][nf], 0, 0, 0);
          accg[mi][nf] = __builtin_amdgcn_mfma_f32_16x16x32_f16(a[mi][ks], bgv, accg[mi][nf], 0, 0, 0);
        }
      }
    }

    // epilogue for this n-half
#pragma unroll
    for (int mi = 0; mi < 2; ++mi) {
      const int mt = mtp * 2 + mi;
#pragma unroll
      for (int nf = 0; nf < 4; ++nf) {
        const int n = h * 128 + nh * 64 + nf * 16 + r16;
        const float bpn = bp[n];
        const float bgn = bg[n];
        const int ks_e = n >> 5;
        const int lane_e = ((n >> 3) & 3) << 4;
        const int og_e = (n >> 3) & 7;
        const int je = n & 7;
#pragma unroll
        for (int reg = 0; reg < 4; ++reg) {
          const int m = mt * 16 + quad * 4 + reg;
          float p = fmaxf(accp[mi][nf][reg] + bpn, 0.f);
          const float gz = accg[mi][nf][reg] + bgn;
          const float gate = 1.f / (1.f + __expf(-gz));
          const float yv =
              (float)y_s[((mt * 8 + ks_e) * 64 + (((m & 15) | lane_e) ^ og_e)) * 8 + je];
          out[(m0 + m) * EW_ + n] = gate * p + (1.f - gate) * yv;
        }
      }
    }
  }
}

extern "C" void kernel_launch(void* const* d_in, const int* in_sizes, int n_in,
                              void* d_out, int out_size, void* d_ws, size_t ws_size,
                              hipStream_t stream) {
  (void)in_sizes; (void)n_in; (void)out_size; (void)ws_size;
  const int*   idx = (const int*)d_in[0];
  const float* emb = (const float*)d_in[1];
  const float* cw  = (const float*)d_in[2];
  const float* cb  = (const float*)d_in[3];
  const float* wp  = (const float*)d_in[4];
  const float* bpp = (const float*)d_in[5];
  const float* wgt = (const float*)d_in[6];
  const float* bgg = (const float*)d_in[7];
  float* out = (float*)d_out;
  _Float16* g_ws = (_Float16*)d_ws;            // 500*256 fp16
  _Float16* wp_f = g_ws + GROWS * EW_;         // 65536 halves, frag order
  _Float16* wg_f = wp_f + EW_ * EW_;           // 65536 halves, frag order

  k_prep<<<GROWS + 32, 256, 0, stream>>>(emb, cw, wp, wgt, g_ws, wp_f, wg_f);
  k_mega<<<NW_ / WPB, 512, 0, stream>>>(idx, g_ws, cb, wp_f, wg_f, bpp, bgg, out);
}